// Round 1
// baseline (527.907 us; speedup 1.0000x reference)
//
#include <hip/hip_runtime.h>
#include <hip/hip_bf16.h>

#define EPS 1e-5f

typedef short s8v __attribute__((ext_vector_type(8)));
typedef float f4v __attribute__((ext_vector_type(4)));

__device__ __forceinline__ unsigned short f2bf(float f) {
  unsigned u = __builtin_bit_cast(unsigned, f);
  u = u + 0x7FFFu + ((u >> 16) & 1u);
  return (unsigned short)(u >> 16);
}
__device__ __forceinline__ float bf2f(unsigned short h) {
  unsigned u = ((unsigned)h) << 16;
  return __builtin_bit_cast(float, u);
}
__device__ __forceinline__ float fast_tanh(float x) {
  float e = __expf(2.0f * x);
  return 1.0f - 2.0f / (e + 1.0f);
}
__device__ __forceinline__ float fast_sigmoid(float x) {
  return 1.0f / (1.0f + __expf(-x));
}
__device__ __forceinline__ float frcp(float x) { return __builtin_amdgcn_rcpf(x); }

// ------ transpose + bf16: W[k][n] f32 -> WT[n][k] bf16 (mq, mk, mv, mb) ------
__global__ __launch_bounds__(256) void transpose_kernel(
    const float* __restrict__ W_mq, const float* __restrict__ W_mk,
    const float* __restrict__ W_mv, const float* __restrict__ W_mb,
    unsigned short* __restrict__ W_mqT, unsigned short* __restrict__ W_mkT,
    unsigned short* __restrict__ W_mvT, unsigned short* __restrict__ W_mbT) {
  __shared__ float tile[32][33];
  int bid = blockIdx.x;
  const float* src; unsigned short* dst; int N, t0;
  if (bid < 64)        { src = W_mq; dst = W_mqT; N = 64;   t0 = bid; }
  else if (bid < 128)  { src = W_mk; dst = W_mkT; N = 64;   t0 = bid - 64; }
  else if (bid < 1152) { src = W_mv; dst = W_mvT; N = 1024; t0 = bid - 128; }
  else                 { src = W_mb; dst = W_mbT; N = 1024; t0 = bid - 1152; }
  const int K = 1024;
  int tk = t0 & 31, tn = t0 >> 5;
  int k0 = tk * 32, n0 = tn * 32;
  int t = threadIdx.x;
  int cr = t >> 5, cc = t & 31;
#pragma unroll
  for (int u = 0; u < 4; u++) {
    int row = cr + u * 8;
    tile[row][cc] = src[(size_t)(k0 + row) * N + n0 + cc];
  }
  __syncthreads();
#pragma unroll
  for (int u = 0; u < 4; u++) {
    int nl = cr + u * 8;
    dst[(size_t)(n0 + nl) * K + k0 + cc] = f2bf(tile[cc][nl]);
  }
}

// ------ Q tile (16 rows) = dpfp(HS @ W_mq), as a 128-thread sub-block --------
union QLdsU { float y[16 * 64]; unsigned short kq[16 * 128]; };

__device__ void q_tile_pair(const float* __restrict__ HS,
                            const unsigned short* __restrict__ W_mqT,
                            unsigned short* __restrict__ Q, int tile,
                            char* qsmem) {
  QLdsU* lds = (QLdsU*)qsmem;
  int t = threadIdx.x & 127, wv = t >> 6, lane = t & 63, m = lane & 15, q = lane >> 4;
  int r0 = tile * 16;
  const float* ap = HS + (size_t)(r0 + m) * 1024 + wv * 512 + q * 8;
  const unsigned short* bp = W_mqT + (size_t)m * 1024 + wv * 512 + q * 8;
  f4v acc[4] = {f4v{0,0,0,0}, f4v{0,0,0,0}, f4v{0,0,0,0}, f4v{0,0,0,0}};
#pragma unroll 4
  for (int ks = 0; ks < 16; ks++) {
    int k0 = ks * 32;
    f4v h0 = *(const f4v*)(ap + k0);
    f4v h1 = *(const f4v*)(ap + k0 + 4);
    s8v a;
    a[0] = (short)f2bf(h0[0]); a[1] = (short)f2bf(h0[1]);
    a[2] = (short)f2bf(h0[2]); a[3] = (short)f2bf(h0[3]);
    a[4] = (short)f2bf(h1[0]); a[5] = (short)f2bf(h1[1]);
    a[6] = (short)f2bf(h1[2]); a[7] = (short)f2bf(h1[3]);
#pragma unroll
    for (int nf = 0; nf < 4; nf++) {
      s8v b = *(const s8v*)(bp + nf * 16384 + k0);
      acc[nf] = __builtin_amdgcn_mfma_f32_16x16x32_bf16(a, b, acc[nf], 0, 0, 0);
    }
  }
  if (wv == 1) {
#pragma unroll
    for (int nf = 0; nf < 4; nf++)
#pragma unroll
      for (int i = 0; i < 4; i++)
        lds->y[(nf * 4 + i) * 64 + lane] = acc[nf][i];
  }
  __syncthreads();
  if (wv == 0) {
#pragma unroll
    for (int nf = 0; nf < 4; nf++)
#pragma unroll
      for (int i = 0; i < 4; i++)
        acc[nf][i] += lds->y[(nf * 4 + i) * 64 + lane];
    int srcl = (lane & 48) | ((m + 15) & 15);
#pragma unroll
    for (int i = 0; i < 4; i++) {
      float yp[4];
#pragma unroll
      for (int nf = 0; nf < 4; nf++) yp[nf] = __shfl(acc[nf][i], srcl);
      int r = q * 4 + i;
#pragma unroll
      for (int nf = 0; nf < 4; nf++) {
        float yv = acc[nf][i];
        float py = (m != 0) ? yp[nf] : (nf > 0 ? yp[nf - 1] : yp[3]);
        bool wrap = (m == 0 && nf == 0);
        float x2lo = wrap ? fmaxf(-py, 0.f) : fmaxf(py, 0.f);
        float x2hi = wrap ? fmaxf(py, 0.f) : fmaxf(-py, 0.f);
        lds->kq[r * 128 + nf * 16 + m]      = f2bf(fmaxf(yv, 0.f) * x2lo);
        lds->kq[r * 128 + 64 + nf * 16 + m] = f2bf(fmaxf(-yv, 0.f) * x2hi);
      }
    }
  }
  __syncthreads();
  {
    int row = t >> 3, ch = t & 7;
    unsigned short* qp = Q + (size_t)(r0 + row) * 128 + ch * 16;
    *(s8v*)(qp)     = *(const s8v*)&lds->kq[row * 128 + ch * 16];
    *(s8v*)(qp + 8) = *(const s8v*)&lds->kq[row * 128 + ch * 16 + 8];
  }
}

// ------ scan role: blocks 0..63, whole 8-segment recurrence ------------------
// blocks 0..15 additionally self-produce the 32 mem-token Q tiles first.
__device__ void scan_role(
    const float* __restrict__ HS, const unsigned short* __restrict__ W_mqT,
    const unsigned short* __restrict__ Qb, const unsigned short* __restrict__ W_mkT,
    const unsigned short* __restrict__ W_mvT, const unsigned short* __restrict__ W_mbT,
    const float* __restrict__ b_mb, const float* __restrict__ MO,
    float* __restrict__ OUT, unsigned short* __restrict__ hist,
    float* __restrict__ zh, unsigned short* __restrict__ mem_bf,
    int* bar, int* qflags, char* smem) {
  float* Wf           = (float*)smem;                    // 32768
  unsigned short* Wbf = (unsigned short*)(smem + 32768); // 16896
  float* y_lds        = (float*)(smem + 49664);          // 4096
  float* k_f          = (float*)(smem + 53760);          // 8192
  unsigned short* k_bf= (unsigned short*)(smem + 61952); // 4352
  float* kden_l       = (float*)(smem + 66304);          // 64
  float* ni_lds       = (float*)(smem + 66368);          // 4160
  float* z_l          = (float*)(smem + 70528);          // 512 -> 71040

  int t = threadIdx.x, wv = t >> 6, lane = t & 63, m = lane & 15, q = lane >> 4;
  int ct = blockIdx.x & 15, b = blockIdx.x >> 4;
  int col = ct * 64 + wv * 16 + m;

  // --- mem-token Q tiles (rows 512..527 of each segment): blocks 0..15 ---
  if (blockIdx.x < 16) {
    int pair = t >> 7;
    int sp = blockIdx.x * 2 + pair;                        // 0..31
    int tile = (sp >> 3) * 264 + (sp & 7) * 33 + 32;       // (b', seg') special
    q_tile_pair(HS, W_mqT, (unsigned short*)Qb, tile, smem + pair * 4096);
    __syncthreads();
    if (t == 0) { __threadfence(); atomicAdd(qflags, 2); }
  }

  for (int i = t; i < 128 * 64; i += 256) Wf[i] = 0.f;
  for (int i = t; i < 64 * 132; i += 256) Wbf[i] = 0;
  if (t < 128) z_l[t] = 0.f;
  float bmb = b_mb[col];
  // wait for all 32 mem-token Q tiles, acquire
  if (t == 0) {
    while (__hip_atomic_load(qflags, __ATOMIC_RELAXED, __HIP_MEMORY_SCOPE_AGENT) < 32)
      __builtin_amdgcn_s_sleep(1);
    __threadfence();
  }
  __syncthreads();

  // prefetch phase-A operands for segment 0
  s8v aq[4]; float mo_pf[4];
  {
    const unsigned short* qp = Qb + ((size_t)b * 4224 + 512 + m) * 128;
#pragma unroll
    for (int ks = 0; ks < 4; ks++) aq[ks] = *(const s8v*)(qp + ks * 32 + q * 8);
    const float* mop = MO + ((size_t)b * 4224 + 512 + q * 4) * 1024 + col;
#pragma unroll
    for (int i = 0; i < 4; i++) mo_pf[i] = mop[(size_t)i * 1024];
  }

  for (int s = 0; s < 8; s++) {
    // ---- phase A: mem-token assoc from registers + LDS state ----
    {
      float dp = 0.f;
#pragma unroll
      for (int ks = 0; ks < 4; ks++)
#pragma unroll
        for (int j = 0; j < 8; j++)
          dp += bf2f((unsigned short)aq[ks][j]) * z_l[ks * 32 + q * 8 + j];
      dp += __shfl_xor(dp, 16);
      dp += __shfl_xor(dp, 32);
      dp += EPS;
      f4v acc = {0, 0, 0, 0};
#pragma unroll
      for (int ks = 0; ks < 4; ks++) {
        s8v bv = *(const s8v*)&Wbf[(wv * 16 + m) * 132 + ks * 32 + q * 8];
        acc = __builtin_amdgcn_mfma_f32_16x16x32_bf16(aq[ks], bv, acc, 0, 0, 0);
      }
      unsigned short* mb = mem_bf + (s & 1) * 65536 + b * 16384;
      size_t grow = (size_t)b * 4224 + s * 528 + 512;
#pragma unroll
      for (int i = 0; i < 4; i++) {
        float rden = frcp(__shfl(dp, q * 4 + i));
        float assoc = acc[i] * rden;
        float mov = mo_pf[i];
        OUT[(grow + q * 4 + i) * 1024 + col] = mov + fast_tanh(assoc);
        mb[(q * 4 + i) * 1024 + col] = f2bf(assoc + mov);
      }
    }
    // ---- per-b grid barrier (16 blocks); also releases hist[s]/zh[s] to workers
    __syncthreads();
    if (t == 0) {
      __threadfence();
      atomicAdd(bar + s * 4 + b, 1);
      while (__hip_atomic_load(bar + s * 4 + b, __ATOMIC_RELAXED,
                               __HIP_MEMORY_SCOPE_AGENT) < 16)
        __builtin_amdgcn_s_sleep(1);
      __threadfence();
    }
    __syncthreads();
    // ---- merged loop: y = mem@W_mkT, v = mem@W_mvT, g = mem@W_mbT ----
    f4v accv = {0,0,0,0}, accg = {0,0,0,0};
    {
      const unsigned short* avp = mem_bf + (s & 1) * 65536 + b * 16384 + m * 1024 + q * 8;
      const unsigned short* bkp = W_mkT + (size_t)(wv * 16 + m) * 1024 + q * 8;
      const unsigned short* bvp = W_mvT + (size_t)col * 1024 + q * 8;
      const unsigned short* bgp = W_mbT + (size_t)col * 1024 + q * 8;
      f4v acy = {0, 0, 0, 0};
#pragma unroll 4
      for (int ks = 0; ks < 32; ks++) {
        s8v av = *(const s8v*)(avp + ks * 32);
        s8v bk = *(const s8v*)(bkp + ks * 32);
        s8v bv = *(const s8v*)(bvp + ks * 32);
        s8v bg = *(const s8v*)(bgp + ks * 32);
        acy  = __builtin_amdgcn_mfma_f32_16x16x32_bf16(av, bk, acy, 0, 0, 0);
        accv = __builtin_amdgcn_mfma_f32_16x16x32_bf16(av, bv, accv, 0, 0, 0);
        accg = __builtin_amdgcn_mfma_f32_16x16x32_bf16(av, bg, accg, 0, 0, 0);
      }
#pragma unroll
      for (int i = 0; i < 4; i++) y_lds[(q * 4 + i) * 64 + wv * 16 + m] = acy[i];
    }
    __syncthreads();
    // ---- k = dpfp(y), kden via 16-lane shfl reduction ----
    {
      int r = t >> 4, jg = t & 15;
      const float* yr = &y_lds[r * 64];
      float pd = 0.f;
#pragma unroll
      for (int u = 0; u < 8; u++) {
        int jj = jg * 8 + u, jm = (jj + 127) & 127;
        float yj = (jj < 64) ? yr[jj] : -yr[jj - 64];
        float ym = (jm < 64) ? yr[jm] : -yr[jm - 64];
        float kv = fmaxf(yj, 0.f) * fmaxf(ym, 0.f);
        k_f[r * 128 + jj] = kv;
        k_bf[r * 136 + jj] = f2bf(kv);
        pd += kv * z_l[jj];
      }
      pd += __shfl_xor(pd, 1);
      pd += __shfl_xor(pd, 2);
      pd += __shfl_xor(pd, 4);
      pd += __shfl_xor(pd, 8);
      if (jg == 0) kden_l[r] = pd + EPS;
    }
    __syncthreads();
    // ---- prev correction + new_info + z update ----
    {
      f4v accp = {0, 0, 0, 0};
#pragma unroll
      for (int ks = 0; ks < 4; ks++) {
        s8v ak = *(const s8v*)&k_bf[m * 136 + ks * 32 + q * 8];
        s8v bm = *(const s8v*)&Wbf[(wv * 16 + m) * 132 + ks * 32 + q * 8];
        accp = __builtin_amdgcn_mfma_f32_16x16x32_bf16(ak, bm, accp, 0, 0, 0);
      }
#pragma unroll
      for (int i = 0; i < 4; i++) {
        int r = q * 4 + i;
        float prev = accp[i] * frcp(kden_l[r]);
        float g = fast_sigmoid(accg[i] + bmb);
        ni_lds[r * 65 + wv * 16 + m] = g * (accv[i] - prev);
      }
      if (t < 128) {
        float ssum = 0.f;
#pragma unroll
        for (int r = 0; r < 16; r++) ssum += k_f[r * 128 + t];
        z_l[t] += ssum;
        if (s < 7) zh[(s + 1) * 512 + b * 128 + t] = z_l[t];
      }
    }
    __syncthreads();
    // ---- phase 4: W += k^T @ ni; dump hist[s+1]; prefetch next phase A ----
    {
      int cl = t & 63, kg = t >> 6;
      float niv[16];
#pragma unroll
      for (int mm = 0; mm < 16; mm++) niv[mm] = ni_lds[mm * 65 + cl];
      float delta[32];
#pragma unroll
      for (int jj = 0; jj < 32; jj++) delta[jj] = 0.f;
#pragma unroll
      for (int mm = 0; mm < 16; mm++) {
        const float* kb = &k_f[mm * 128 + kg * 32];
        float nv = niv[mm];
#pragma unroll
        for (int ch = 0; ch < 8; ch++) {
          f4v kv4 = *(const f4v*)(kb + ch * 4);
#pragma unroll
          for (int jj = 0; jj < 4; jj++) delta[ch * 4 + jj] += kv4[jj] * nv;
        }
      }
      unsigned short* hdst = hist + (size_t)(s + 1) * 524288 +
                             ((size_t)b * 1024 + ct * 64 + cl) * 128 + kg * 32;
#pragma unroll
      for (int c8 = 0; c8 < 4; c8++) {
        s8v pk;
#pragma unroll
        for (int u = 0; u < 8; u++) {
          int kk = kg * 32 + c8 * 8 + u;
          float nv = Wf[kk * 64 + cl] + delta[c8 * 8 + u];
          Wf[kk * 64 + cl] = nv;
          pk[u] = (short)f2bf(nv);
        }
        *(s8v*)&Wbf[cl * 132 + kg * 32 + c8 * 8] = pk;
        if (s < 7) *(s8v*)(hdst + c8 * 8) = pk;
      }
      if (s < 7) {
        const unsigned short* qp = Qb + ((size_t)b * 4224 + (s + 1) * 528 + 512 + m) * 128;
#pragma unroll
        for (int ks = 0; ks < 4; ks++) aq[ks] = *(const s8v*)(qp + ks * 32 + q * 8);
        const float* mop = MO + ((size_t)b * 4224 + (s + 1) * 528 + 512 + q * 4) * 1024 + col;
#pragma unroll
        for (int i = 0; i < 4; i++) mo_pf[i] = mop[(size_t)i * 1024];
      }
    }
    __syncthreads();
  }
}

// ------ worker role: blocks 64..255 — regular Q tiles, then gated a_bulk -----
__device__ void worker_role(
    const float* __restrict__ HS, const unsigned short* __restrict__ W_mqT,
    unsigned short* __restrict__ Qb, const unsigned short* __restrict__ hist,
    const float* __restrict__ zh, const float* __restrict__ MO,
    float* __restrict__ OUT, int* bar, int* qflags, char* smem) {
  int w = (int)blockIdx.x - 64;  // 0..191
  int t = threadIdx.x;
  int pair = t >> 7;
  // ---- Q phase: 512 regular pair-tiles (2 tiles/block-iteration) ----
  int np = 0;
  for (int p = w; p < 512; p += 192) {
    int rr = 2 * p + pair;  // regular rank 0..1023
    int tile = (rr >> 8) * 264 + ((rr & 255) >> 5) * 33 + (rr & 31);
    q_tile_pair(HS, W_mqT, Qb, tile, smem + pair * 4096);
    np++;
    __syncthreads();  // protect LDS reuse across iterations
  }
  if (t == 0) { __threadfence(); atomicAdd(qflags + 1, np); }
  // ---- seg-0 bulk tiles: OUT = MO (W=0, z=0 => assoc = 0) ----
  for (int idx = w; idx < 512; idx += 192) {
    int b = idx & 3, ct = (idx >> 2) & 15, rt4 = idx >> 6;
    int r = t >> 2, cchunk = (t & 3) * 16;
    size_t rbase = ((size_t)b * 4224 + (size_t)rt4 * 64 + r) * 1024 + ct * 64 + cchunk;
#pragma unroll
    for (int u = 0; u < 4; u++)
      *(f4v*)(OUT + rbase + u * 4) = *(const f4v*)(MO + rbase + u * 4);
  }
  // ---- wait all regular Q done, acquire ----
  if (t == 0) {
    while (__hip_atomic_load(qflags + 1, __ATOMIC_RELAXED, __HIP_MEMORY_SCOPE_AGENT) < 512)
      __builtin_amdgcn_s_sleep(1);
    __threadfence();
  }
  __syncthreads();
  // ---- gated bulk tiles (seg >= 1): ready when bar[seg*4+b] == 16 ----
  int wv = t >> 6, lane = t & 63, m = lane & 15, q = lane >> 4;
  float* as_l = (float*)smem;  // 64*65*4 = 16640 B
  for (int idx = 512 + w; idx < 4096; idx += 192) {
    int seg = idx >> 9, inner = idx & 511;
    int b = inner & 3, ct = (inner >> 2) & 15, rt4 = inner >> 6;
    if (t == 0) {
      while (__hip_atomic_load(bar + seg * 4 + b, __ATOMIC_RELAXED,
                               __HIP_MEMORY_SCOPE_AGENT) < 16)
        __builtin_amdgcn_s_sleep(2);
      __threadfence();
    }
    __syncthreads();
    const unsigned short* Wm = hist + (size_t)seg * 524288 + ((size_t)b * 1024 + ct * 64) * 128;
    const float* zp = zh + seg * 512 + b * 128;
    size_t grow = (size_t)b * 4224 + (size_t)seg * 528 + rt4 * 64 + wv * 16;
    const unsigned short* qp = Qb + (grow + m) * 128;
    s8v a[4];
    float dp = 0.f;
#pragma unroll
    for (int ks = 0; ks < 4; ks++) {
      a[ks] = *(const s8v*)(qp + ks * 32 + q * 8);
      f4v z0 = *(const f4v*)(zp + ks * 32 + q * 8);
      f4v z1 = *(const f4v*)(zp + ks * 32 + q * 8 + 4);
#pragma unroll
      for (int j = 0; j < 4; j++) dp += bf2f((unsigned short)a[ks][j]) * z0[j];
#pragma unroll
      for (int j = 0; j < 4; j++) dp += bf2f((unsigned short)a[ks][j + 4]) * z1[j];
    }
    dp += __shfl_xor(dp, 16);
    dp += __shfl_xor(dp, 32);
    dp += EPS;
    f4v acc[4] = {f4v{0,0,0,0}, f4v{0,0,0,0}, f4v{0,0,0,0}, f4v{0,0,0,0}};
#pragma unroll
    for (int ks = 0; ks < 4; ks++) {
#pragma unroll
      for (int nf = 0; nf < 4; nf++) {
        s8v bv = *(const s8v*)(Wm + (size_t)(nf * 16 + m) * 128 + ks * 32 + q * 8);
        acc[nf] = __builtin_amdgcn_mfma_f32_16x16x32_bf16(a[ks], bv, acc[nf], 0, 0, 0);
      }
    }
#pragma unroll
    for (int i = 0; i < 4; i++) {
      float rden = frcp(__shfl(dp, q * 4 + i));
#pragma unroll
      for (int nf = 0; nf < 4; nf++)
        as_l[(wv * 16 + q * 4 + i) * 65 + nf * 16 + m] = acc[nf][i] * rden;
    }
    __syncthreads();
    {
      int r = t >> 2, cchunk = (t & 3) * 16;
      size_t rbase = (grow - wv * 16 + r) * 1024 + ct * 64 + cchunk;
      const float* ar = &as_l[r * 65 + cchunk];
#pragma unroll
      for (int u = 0; u < 4; u++) {
        f4v mo = *(const f4v*)(MO + rbase + u * 4);
        f4v o;
#pragma unroll
        for (int j = 0; j < 4; j++) o[j] = mo[j] + fast_tanh(ar[u * 4 + j]);
        *(f4v*)(OUT + rbase + u * 4) = o;
      }
    }
    __syncthreads();  // before next tile reuses as_l
  }
}

// ------ fused: scan (64 blocks) + q/a_bulk workers (192 blocks), 1 dispatch --
// Co-residency: LDS 71040 B -> 2 blk/CU; VGPR <=512 -> >=1 blk/CU; grid 256
// <= capacity, so all blocks resident and the flag protocol cannot deadlock.
__global__ __launch_bounds__(256, 1) void fused_kernel(
    const float* __restrict__ HS, const unsigned short* __restrict__ W_mqT,
    const unsigned short* __restrict__ W_mkT, const unsigned short* __restrict__ W_mvT,
    const unsigned short* __restrict__ W_mbT, const float* __restrict__ b_mb,
    const float* __restrict__ MO, float* __restrict__ OUT,
    unsigned short* __restrict__ Qb, unsigned short* __restrict__ hist,
    float* __restrict__ zh, unsigned short* __restrict__ mem_bf,
    int* bar, int* qflags) {
  __shared__ __align__(16) char smem[71040];
  if (blockIdx.x < 64) {
    scan_role(HS, W_mqT, Qb, W_mkT, W_mvT, W_mbT, b_mb, MO, OUT,
              hist, zh, mem_bf, bar, qflags, smem);
  } else {
    worker_role(HS, W_mqT, Qb, hist, zh, MO, OUT, bar, qflags, smem);
  }
}

extern "C" void kernel_launch(void* const* d_in, const int* in_sizes, int n_in,
                              void* d_out, int out_size, void* d_ws, size_t ws_size,
                              hipStream_t stream) {
  const float* HS  = (const float*)d_in[0];
  const float* MO  = (const float*)d_in[1];
  const float* W_mq = (const float*)d_in[2];
  const float* W_mk = (const float*)d_in[3];
  const float* W_mv = (const float*)d_in[4];
  const float* W_mb = (const float*)d_in[5];
  const float* b_mb = (const float*)d_in[6];
  float* OUT = (float*)d_out;

  char* wsb = (char*)d_ws;
  unsigned short* hist   = (unsigned short*)(wsb + 0);        // slots 1..7 used
  float*          zh     = (float*)(wsb + 8388608);           // slots 1..7 used
  unsigned short* Qb     = (unsigned short*)(wsb + 8404992);  // 4,325,376
  unsigned short* W_mqT  = (unsigned short*)(wsb + 12730368); // 131,072
  unsigned short* W_mkT  = (unsigned short*)(wsb + 12861440); // 131,072
  unsigned short* W_mvT  = (unsigned short*)(wsb + 12992512); // 2,097,152
  unsigned short* W_mbT  = (unsigned short*)(wsb + 15089664); // 2,097,152
  unsigned short* mem_bf = (unsigned short*)(wsb + 17186816); // 2 x 131,072
  int*            bar    = (int*)(wsb + 17448960);            // 128 B
  int*            qflags = (int*)(wsb + 0);                   // inside unused hist slot 0
  // total ~17.45 MB

  (void)hipMemsetAsync(wsb, 0, 256, stream);   // qflags (hist slot 0 is unused now)
  (void)hipMemsetAsync(bar, 0, 128, stream);
  transpose_kernel<<<2176, 256, 0, stream>>>(W_mq, W_mk, W_mv, W_mb,
                                             W_mqT, W_mkT, W_mvT, W_mbT);
  fused_kernel<<<256, 256, 0, stream>>>(HS, W_mqT, W_mkT, W_mvT, W_mbT, b_mb,
                                        MO, OUT, Qb, hist, zh, mem_bf, bar, qflags);
}